// Round 14
// baseline (229.954 us; speedup 1.0000x reference)
//
#include <hip/hip_runtime.h>

// ---------------------------------------------------------------------------
// MambaBlock forward, MI355X gfx950.
// CONTRACT (pinned R4): inputs f32, OUTPUT f32. ws = 256 MiB (pinned R9).
// Internals: bf16 GEMM operands (MFMA 16x16x32), f32 accumulation/scan.
// R14: R13 green base + (a) NC 64->32: halves hend/hstart HBM round-trip
// (67->33 MB) and combine serial depth; scan grids 512 blocks = 2 blocks/CU
// (still co-residency regime); (b) conv_silu 2-wide in d (packed u32 bf16).
// LESSONS pinned: split-K reduce stays a SEPARATE kernel (R12: intra-kernel
// device-scope fence = L2 writeback across 8 non-coherent XCDs, +100us);
// no cooperative launch (R11 failed to launch under graph capture).
// B=2, S=1024, D_MODEL=1024, D_INNER=2048, D_STATE=16, D_CONV=4.
// ---------------------------------------------------------------------------

#define NTOK   2048          // BATCH*SEQ
#define NC     32            // scan chunks per sequence
#define TC     32            // steps per chunk (SEQ/NC)

typedef unsigned short u16;
typedef short short8 __attribute__((ext_vector_type(8)));
typedef float f32x4 __attribute__((ext_vector_type(4)));

__device__ __forceinline__ float bf2f(u16 v) {
    union { unsigned int u; float f; } w; w.u = ((unsigned int)v) << 16; return w.f;
}
__device__ __forceinline__ u16 f2bf(float f) {
    union { float f; unsigned int u; } w; w.f = f;
    unsigned int u = w.u;
    return (u16)((u + 0x7fffu + ((u >> 16) & 1u)) >> 16);
}

// Async global->LDS, 16B per lane; LDS dst wave-uniform base (m97/m104/m108).
__device__ __forceinline__ void gload_lds16(const u16* g, u16* l) {
    __builtin_amdgcn_global_load_lds(
        (const __attribute__((address_space(1))) void*)g,
        (__attribute__((address_space(3))) void*)l, 16, 0, 0);
}

// fast softplus: max(x,0) + log(1+exp(-|x|))
__device__ __forceinline__ float softplus_f(float x) {
    return fmaxf(x, 0.f) + __logf(1.f + __expf(-__builtin_fabsf(x)));
}

// ---------------------------------------------------------------------------
// Fused prep: block-range dispatch.
//   [0, 2048)        cast x f32 -> bf16 (float4 / 4 elems per thread)
//   [2048, 6144)     transpose W_in  [1024][4096] -> WinT  [4096][1024] bf16
//   [6144, 8192)     transpose W_out [2048][1024] -> WoutT [1024][2048] bf16
//   [8192, 9216)     W_xproj [2048][33] -> WxpT [128][2048] bf16, zero-pad
// ---------------------------------------------------------------------------
__device__ __forceinline__ void transpose_tile(const float* __restrict__ in,
                                               u16* __restrict__ out,
                                               int R, int C, int n0, int k0,
                                               int tid) {
    __shared__ float tile[32][33];
    const int tx = tid & 31, ty = tid >> 5;   // 32x8
    #pragma unroll
    for (int i = 0; i < 32; i += 8)
        tile[ty + i][tx] = in[(size_t)(k0 + ty + i) * C + n0 + tx];
    __syncthreads();
    #pragma unroll
    for (int i = 0; i < 32; i += 8)
        out[(size_t)(n0 + ty + i) * R + k0 + tx] = f2bf(tile[tx][ty + i]);
}

__global__ __launch_bounds__(256)
void prep_all(const float* __restrict__ x, const float* __restrict__ W_in,
              const float* __restrict__ W_out, const float* __restrict__ W_xproj,
              u16* __restrict__ xbf, u16* __restrict__ WinT,
              u16* __restrict__ WoutT, u16* __restrict__ WxpT) {
    const int tid = threadIdx.x;
    int blk = blockIdx.x;
    if (blk < 2048) {                          // cast x (2M elems, 4/thread)
        int base = (blk * 256 + tid) * 4;
        float4 v = *(const float4*)(x + base);
        ushort4 o;
        o.x = f2bf(v.x); o.y = f2bf(v.y); o.z = f2bf(v.z); o.w = f2bf(v.w);
        *(ushort4*)(xbf + base) = o;
        return;
    }
    blk -= 2048;
    if (blk < 4096) {                          // W_in: R=1024, C=4096
        transpose_tile(W_in, WinT, 1024, 4096, (blk & 127) * 32, (blk >> 7) * 32, tid);
        return;
    }
    blk -= 4096;
    if (blk < 2048) {                          // W_out: R=2048, C=1024
        transpose_tile(W_out, WoutT, 2048, 1024, (blk & 31) * 32, (blk >> 5) * 32, tid);
        return;
    }
    blk -= 2048;
    {                                          // WxpT pad+transpose
        int gid = blk * 256 + tid;
        int k = gid & 2047;
        int n = gid >> 11;
        WxpT[(size_t)n * 2048 + k] = (n < 33) ? f2bf(W_xproj[(size_t)k * 33 + n]) : (u16)0;
    }
}

// ---------------------------------------------------------------------------
// MFMA GEMM (R10-verified): C[M][N] = A[M][K] * Bt[N][K]^T, 128x128 tile,
// BK=64 staged as two 128x32 half-buffers (m97-proven 64B LDS row stride;
// global_load_lds forbids padding). OUT_MODE: 0 = f32 partial at
// blockIdx.z*M*N (split-K, atomic-free), 2 = bf16 store (gridDim.z==1).
// ---------------------------------------------------------------------------
template <int OUT_MODE>
__global__ __launch_bounds__(256)
void gemm_bt(const u16* __restrict__ A, const u16* __restrict__ Bt,
             void* __restrict__ Cv, int M, int N, int K) {
    __shared__ __align__(16) u16 As[2][128 * 32];
    __shared__ __align__(16) u16 Bs[2][128 * 32];

    const int tid  = threadIdx.x;
    const int lane = tid & 63;
    const int w    = tid >> 6;
    const int wm   = (w >> 1) * 64;
    const int wn   = (w & 1) * 64;
    const int r    = lane & 15;
    const int q    = lane >> 4;
    const int m0   = blockIdx.x * 128;
    const int n0   = blockIdx.y * 128;
    const int kChunk = K / gridDim.z;
    const int k0   = blockIdx.z * kChunk;

    f32x4 acc[4][4];
    #pragma unroll
    for (int i = 0; i < 4; ++i)
        #pragma unroll
        for (int j = 0; j < 4; ++j)
            acc[i][j] = (f32x4){0.f, 0.f, 0.f, 0.f};

    for (int kk = k0; kk < k0 + kChunk; kk += 64) {
        __syncthreads();
        #pragma unroll
        for (int i = 0; i < 4; ++i) {
            int half = i >> 1;
            int c    = ((i & 1) << 8) + tid;
            int row  = c >> 2;
            int kc   = (c & 3) << 3;
            int wb   = (((i & 1) << 8) + (tid & 192)) * 8;
            gload_lds16(&A[(size_t)(m0 + row) * K + kk + half * 32 + kc],
                        &As[half][wb]);
            gload_lds16(&Bt[(size_t)(n0 + row) * K + kk + half * 32 + kc],
                        &Bs[half][wb]);
        }
        __syncthreads();

        #pragma unroll
        for (int half = 0; half < 2; ++half) {
            short8 af[4], bf[4];
            #pragma unroll
            for (int mt = 0; mt < 4; ++mt)
                af[mt] = *(const short8*)(&As[half][(wm + mt * 16 + r) * 32 + q * 8]);
            #pragma unroll
            for (int nt = 0; nt < 4; ++nt)
                bf[nt] = *(const short8*)(&Bs[half][(wn + nt * 16 + r) * 32 + q * 8]);

            #pragma unroll
            for (int mt = 0; mt < 4; ++mt)
                #pragma unroll
                for (int nt = 0; nt < 4; ++nt)
                    acc[mt][nt] = __builtin_amdgcn_mfma_f32_16x16x32_bf16(
                        af[mt], bf[nt], acc[mt][nt], 0, 0, 0);
        }
    }

    float* Cp = (float*)Cv + (size_t)blockIdx.z * M * N;
    #pragma unroll
    for (int mt = 0; mt < 4; ++mt) {
        #pragma unroll
        for (int nt = 0; nt < 4; ++nt) {
            #pragma unroll
            for (int i = 0; i < 4; ++i) {
                int row = m0 + wm + mt * 16 + q * 4 + i;
                int col = n0 + wn + nt * 16 + r;
                float v = acc[mt][nt][i];
                size_t idx = (size_t)row * N + col;
                if (OUT_MODE == 0) Cp[idx] = v;
                else               ((u16*)Cv)[idx] = f2bf(v);
            }
        }
    }
}

// reduce split-K partials: o4[i] = sum_z p4[z*n4+i]   (float4 lanes)
// Separate kernel ON PURPOSE — kernel boundary is the cheap device-scope
// fence on CDNA4 (R12: intra-kernel __threadfence cost ~100us across XCDs).
__global__ __launch_bounds__(256)
void reduce_parts(const float4* __restrict__ p, float4* __restrict__ o,
                  int n4, int parts) {
    int i = blockIdx.x * 256 + threadIdx.x;
    if (i >= n4) return;
    float4 s = p[i];
    for (int z = 1; z < parts; ++z) {
        float4 v = p[(size_t)z * n4 + i];
        s.x += v.x; s.y += v.y; s.z += v.z; s.w += v.w;
    }
    o[i] = s;
}

// ---------------------------------------------------------------------------
// Depthwise causal conv (4-tap) + bias + SiLU. 2 channels per thread
// (packed u32 bf16 loads/stores).
// ---------------------------------------------------------------------------
__global__ __launch_bounds__(256)
void conv_silu(const u16* __restrict__ xz, const float* __restrict__ cw,
               const float* __restrict__ cb, u16* __restrict__ xcb) {
    const int dp  = blockIdx.x * 256 + threadIdx.x;   // 0..1023 (pair idx)
    const int d   = dp * 2;
    const int tok = blockIdx.y;
    const int b   = tok >> 10;
    const int t   = tok & 1023;
    float s0 = cb[d];
    float s1 = cb[d + 1];
    const float4 w0 = *(const float4*)(cw + d * 4);        // taps for d
    const float4 w1 = *(const float4*)(cw + d * 4 + 4);    // taps for d+1
    const float wa0[4] = {w0.x, w0.y, w0.z, w0.w};
    const float wa1[4] = {w1.x, w1.y, w1.z, w1.w};
    #pragma unroll
    for (int k = 0; k < 4; ++k) {
        int tt = t - 3 + k;
        if (tt >= 0) {
            unsigned int pk = *(const unsigned int*)
                (&xz[(size_t)(b * 1024 + tt) * 4096 + d]);
            s0 += bf2f((u16)(pk & 0xffffu)) * wa0[k];
            s1 += bf2f((u16)(pk >> 16)) * wa1[k];
        }
    }
    float sl0 = s0 / (1.f + __expf(-s0));
    float sl1 = s1 / (1.f + __expf(-s1));
    unsigned int po = (unsigned int)f2bf(sl0) | ((unsigned int)f2bf(sl1) << 16);
    *(unsigned int*)(&xcb[(size_t)tok * 2048 + d]) = po;
}

// dA powers tree: dA[n] = e1^(n+1), dep depth ~3.
__device__ __forceinline__ void pow_tree(float e1, float* dA) {
    float e2 = e1 * e1, e4 = e2 * e2, e8 = e4 * e4;
    dA[0] = e1;       dA[1] = e2;       dA[2] = e2 * e1;  dA[3] = e4;
    dA[4] = e4 * e1;  dA[5] = e4 * e2;  dA[6] = e4 * dA[2]; dA[7] = e8;
    dA[8] = e8 * e1;  dA[9] = e8 * e2;  dA[10] = e8 * dA[2]; dA[11] = e8 * e4;
    dA[12] = e8 * dA[4]; dA[13] = e8 * dA[5]; dA[14] = e8 * dA[6]; dA[15] = e8 * e8;
}

// ---------------------------------------------------------------------------
// Chunked selective scan (R10-verified structure; NC=32/TC=32). Lanes over d;
// 16 states in regs; xp tile in LDS. xp row stride 128: [0]=dt_raw,
// [1..16]=B, [17..32]=C. Chunk summary: hend[16] + Sdl (Sum delta).
// ---------------------------------------------------------------------------
__global__ __launch_bounds__(256)
void scan_pass1(const u16* __restrict__ xcb, const float* __restrict__ xp,
                const float* __restrict__ W_dt, const float* __restrict__ b_dt,
                const float* __restrict__ A_log,
                float* __restrict__ Sdl, float* __restrict__ hend) {
    const int c  = blockIdx.x;
    const int dg = blockIdx.y;
    const int b  = blockIdx.z;
    const int tid = threadIdx.x;
    const int d  = dg * 256 + tid;
    const int tok0 = b * 1024 + c * TC;

    __shared__ float xps[TC][36];
    for (int e = tid; e < TC * 33; e += 256) {
        int t = (e * 993) >> 15;     // e/33, exact for e < 32736
        int j = e - t * 33;
        xps[t][j] = xp[(size_t)(tok0 + t) * 128 + j];
    }
    __syncthreads();

    float a[16];
    bool fast = true;
    #pragma unroll
    for (int n = 0; n < 16; ++n) {
        a[n] = -__expf(A_log[n]);
        fast = fast && (__builtin_fabsf(a[n] + (float)(n + 1)) < 1e-3f * (n + 1));
    }

    const float wdt = W_dt[d];
    const float bdt = b_dt[d];

    float h[16];
    #pragma unroll
    for (int n = 0; n < 16; ++n) h[n] = 0.f;
    float sdl = 0.f;

    for (int t = 0; t < TC; ++t) {
        const int tok = tok0 + t;
        const float dl = softplus_f(xps[t][0] * wdt + bdt);
        sdl += dl;
        const float xv = bf2f(xcb[(size_t)tok * 2048 + d]);
        const float wv = dl * xv;
        if (fast) {
            float dA[16];
            pow_tree(__expf(-dl), dA);
            #pragma unroll
            for (int n = 0; n < 16; ++n)
                h[n] = fmaf(dA[n], h[n], wv * xps[t][1 + n]);
        } else {
            #pragma unroll
            for (int n = 0; n < 16; ++n)
                h[n] = fmaf(__expf(dl * a[n]), h[n], wv * xps[t][1 + n]);
        }
    }

    Sdl[(size_t)(b * NC + c) * 2048 + d] = sdl;
    #pragma unroll
    for (int n = 0; n < 16; ++n)
        hend[((size_t)((b * NC + c) * 16 + n)) * 2048 + d] = h[n];
}

// Sequential combine (coalesced over d); writes separate __restrict__ hstart
// (R10: alias-free lets loads pipeline past stores).
__global__ __launch_bounds__(256)
void scan_combine(const float* __restrict__ Sdl, const float* __restrict__ A_log,
                  const float* __restrict__ hend, float* __restrict__ hstart) {
    const int gid = blockIdx.x * 256 + threadIdx.x;   // 2*16*2048 threads
    const int d = gid & 2047;
    const int n = (gid >> 11) & 15;
    const int b = gid >> 15;
    const float an = -__expf(A_log[n]);
    float H = 0.f;
    #pragma unroll 4
    for (int c = 0; c < NC; ++c) {
        size_t cidx = (size_t)(b * NC + c);
        float s  = Sdl[cidx * 2048 + d];
        size_t idx = (cidx * 16 + n) * 2048 + d;
        float he = hend[idx];
        hstart[idx] = H;               // start state for chunk c
        H = fmaf(__expf(an * s), H, he);
    }
}

__global__ __launch_bounds__(256)
void scan_pass2(const u16* __restrict__ xcb, const float* __restrict__ xp,
                const float* __restrict__ W_dt, const float* __restrict__ b_dt,
                const float* __restrict__ A_log, const float* __restrict__ Hstart,
                const float* __restrict__ Dp, const u16* __restrict__ xz,
                u16* __restrict__ ybuf) {
    const int c  = blockIdx.x;
    const int dg = blockIdx.y;
    const int b  = blockIdx.z;
    const int tid = threadIdx.x;
    const int d  = dg * 256 + tid;
    const int tok0 = b * 1024 + c * TC;

    __shared__ float xps[TC][36];
    for (int e = tid; e < TC * 33; e += 256) {
        int t = (e * 993) >> 15;
        int j = e - t * 33;
        xps[t][j] = xp[(size_t)(tok0 + t) * 128 + j];
    }
    __syncthreads();

    float a[16];
    bool fast = true;
    #pragma unroll
    for (int n = 0; n < 16; ++n) {
        a[n] = -__expf(A_log[n]);
        fast = fast && (__builtin_fabsf(a[n] + (float)(n + 1)) < 1e-3f * (n + 1));
    }

    const float wdt = W_dt[d];
    const float bdt = b_dt[d];

    float h[16];
    #pragma unroll
    for (int n = 0; n < 16; ++n)
        h[n] = Hstart[((size_t)((b * NC + c) * 16 + n)) * 2048 + d];

    const float Dd = Dp[d];
    for (int t = 0; t < TC; ++t) {
        const int tok = tok0 + t;
        const float dl = softplus_f(xps[t][0] * wdt + bdt);
        const float xv = bf2f(xcb[(size_t)tok * 2048 + d]);
        const float wv = dl * xv;
        if (fast) {
            float dA[16];
            pow_tree(__expf(-dl), dA);
            #pragma unroll
            for (int n = 0; n < 16; ++n)
                h[n] = fmaf(dA[n], h[n], wv * xps[t][1 + n]);
        } else {
            #pragma unroll
            for (int n = 0; n < 16; ++n)
                h[n] = fmaf(__expf(dl * a[n]), h[n], wv * xps[t][1 + n]);
        }
        float y0 = 0.f, y1 = 0.f, y2 = 0.f, y3 = 0.f;
        #pragma unroll
        for (int n = 0; n < 16; n += 4) {
            y0 = fmaf(h[n + 0], xps[t][17 + n + 0], y0);
            y1 = fmaf(h[n + 1], xps[t][17 + n + 1], y1);
            y2 = fmaf(h[n + 2], xps[t][17 + n + 2], y2);
            y3 = fmaf(h[n + 3], xps[t][17 + n + 3], y3);
        }
        float y = (y0 + y1) + (y2 + y3);
        y = fmaf(Dd, xv, y);
        float zv = bf2f(xz[(size_t)tok * 4096 + 2048 + d]);
        float sz = zv / (1.f + __expf(-zv));
        ybuf[(size_t)tok * 2048 + d] = f2bf(y * sz);
    }
}

// ---------------------------------------------------------------------------
extern "C" void kernel_launch(void* const* d_in, const int* in_sizes, int n_in,
                              void* d_out, int out_size, void* d_ws, size_t ws_size,
                              hipStream_t stream) {
    const float* x       = (const float*)d_in[0];
    const float* W_in    = (const float*)d_in[1];
    const float* conv_w  = (const float*)d_in[2];
    const float* conv_b  = (const float*)d_in[3];
    const float* W_xproj = (const float*)d_in[4];
    const float* W_dt    = (const float*)d_in[5];
    const float* b_dt    = (const float*)d_in[6];
    const float* A_log   = (const float*)d_in[7];
    const float* Dp      = (const float*)d_in[8];
    const float* W_out   = (const float*)d_in[9];
    float* out = (float*)d_out;                     // [2][1024][1024] f32

    char* ws = (char*)d_ws;
    size_t off = 0;
    auto alloc = [&](size_t bytes) -> void* {
        void* p = ws + off;
        off += (bytes + 255) & ~(size_t)255;
        return p;
    };

    u16*   xbf    = (u16*)  alloc((size_t)NTOK * 1024 * 2);
    u16*   xz     = (u16*)  alloc((size_t)NTOK * 4096 * 2);
    u16*   WinT   = (u16*)  alloc((size_t)4096 * 1024 * 2);
    u16*   WoutT  = (u16*)  alloc((size_t)1024 * 2048 * 2);
    u16*   WxpT   = (u16*)  alloc((size_t)128 * 2048 * 2);
    u16*   xcb    = (u16*)  alloc((size_t)NTOK * 2048 * 2);
    float* xpp    = (float*)alloc((size_t)8 * NTOK * 128 * 4);     //  8.4 MB
    float* xp     = (float*)alloc((size_t)NTOK * 128 * 4);
    u16*   ybuf   = (u16*)  alloc((size_t)NTOK * 2048 * 2);
    float* Sdl    = (float*)alloc((size_t)2 * NC * 2048 * 4);
    float* hend   = (float*)alloc((size_t)2 * NC * 16 * 2048 * 4); //  8.4 MB
    float* hstart = (float*)alloc((size_t)2 * NC * 16 * 2048 * 4); //  8.4 MB
    float* op     = (float*)alloc((size_t)4 * NTOK * 1024 * 4);    // 33.6 MB

    const int ws_ok = (off <= ws_size);   // ws = 256 MiB; total ~103 MB
    if (ws_ok) {
        // fused prep: cast x (float4), transpose W_in/W_out, pad W_xproj
        prep_all<<<9216, 256, 0, stream>>>(x, W_in, W_out, W_xproj,
                                           xbf, WinT, WoutT, WxpT);

        // GEMM1: xz = xbf @ W_in (bf16 out), 512 blocks, 16 K-rounds
        gemm_bt<2><<<dim3(16, 32, 1), 256, 0, stream>>>(xbf, WinT, xz,
                                                        2048, 4096, 1024);

        conv_silu<<<dim3(4, NTOK), 256, 0, stream>>>(xz, conv_w, conv_b, xcb);

        // xproj: split-K=8 partials (atomic-free), then reduce
        gemm_bt<0><<<dim3(16, 1, 8), 256, 0, stream>>>(xcb, WxpT, xpp,
                                                       2048, 128, 2048);
        reduce_parts<<<(NTOK * 128 / 4) / 256, 256, 0, stream>>>(
            (const float4*)xpp, (float4*)xp, NTOK * 128 / 4, 8);

        // chunked scan (NC=32: 512 blocks/pass, 2 blocks/CU)
        scan_pass1<<<dim3(NC, 8, 2), 256, 0, stream>>>(xcb, xp, W_dt, b_dt, A_log,
                                                       Sdl, hend);
        scan_combine<<<(2 * 16 * 2048) / 256, 256, 0, stream>>>(Sdl, A_log,
                                                                hend, hstart);
        scan_pass2<<<dim3(NC, 8, 2), 256, 0, stream>>>(xcb, xp, W_dt, b_dt, A_log,
                                                       hstart, Dp, xz, ybuf);

        // GEMM2: split-K=4 partials (atomic-free), then reduce into d_out
        gemm_bt<0><<<dim3(16, 8, 4), 256, 0, stream>>>(ybuf, WoutT, op,
                                                       2048, 1024, 2048);
        reduce_parts<<<(NTOK * 1024 / 4) / 256, 256, 0, stream>>>(
            (const float4*)op, (float4*)out, NTOK * 1024 / 4, 4);
    }
}

// Round 15
// 225.599 us; speedup vs baseline: 1.0193x; 1.0193x over previous
//
#include <hip/hip_runtime.h>

// ---------------------------------------------------------------------------
// MambaBlock forward, MI355X gfx950.  FINAL CONFIG (= R13, measured 225.7us).
// CONTRACT (pinned R4): inputs f32, OUTPUT f32. ws = 256 MiB (pinned R9).
// Internals: bf16 GEMM operands (MFMA 16x16x32), f32 accumulation/scan.
// Session lessons pinned in structure:
//  - NC=64/TC=16: 4 blocks/CU on scan passes beats halved state traffic
//    (R14: NC=32 regressed +4.3us — serial chains are latency-bound).
//  - split-K reduce stays a SEPARATE kernel: kernel boundary is the cheap
//    device-scope fence on CDNA4 (R12: intra-kernel __threadfence = L2
//    writeback across 8 non-coherent XCDs, +100us/GEMM).
//  - no cooperative launch under graph capture (R11 failed to launch).
//  - combine: coalesced over d, alias-free in/out buffers (R8/R10 evidence).
//  - GEMM: BK=64 as two 128x32 half-buffers, global_load_lds width=16
//    (m97 pattern; LDS dst is wave-uniform base, padding forbidden).
// B=2, S=1024, D_MODEL=1024, D_INNER=2048, D_STATE=16, D_CONV=4.
// ---------------------------------------------------------------------------

#define NTOK   2048          // BATCH*SEQ
#define NC     64            // scan chunks per sequence
#define TC     16            // steps per chunk (SEQ/NC)

typedef unsigned short u16;
typedef short short8 __attribute__((ext_vector_type(8)));
typedef float f32x4 __attribute__((ext_vector_type(4)));

__device__ __forceinline__ float bf2f(u16 v) {
    union { unsigned int u; float f; } w; w.u = ((unsigned int)v) << 16; return w.f;
}
__device__ __forceinline__ u16 f2bf(float f) {
    union { float f; unsigned int u; } w; w.f = f;
    unsigned int u = w.u;
    return (u16)((u + 0x7fffu + ((u >> 16) & 1u)) >> 16);
}

// Async global->LDS, 16B per lane; LDS dst wave-uniform base (m97/m104/m108).
__device__ __forceinline__ void gload_lds16(const u16* g, u16* l) {
    __builtin_amdgcn_global_load_lds(
        (const __attribute__((address_space(1))) void*)g,
        (__attribute__((address_space(3))) void*)l, 16, 0, 0);
}

// fast softplus: max(x,0) + log(1+exp(-|x|))
__device__ __forceinline__ float softplus_f(float x) {
    return fmaxf(x, 0.f) + __logf(1.f + __expf(-__builtin_fabsf(x)));
}

// ---------------------------------------------------------------------------
// Fused prep: block-range dispatch.
//   [0, 2048)        cast x f32 -> bf16 (float4 / 4 elems per thread)
//   [2048, 6144)     transpose W_in  [1024][4096] -> WinT  [4096][1024] bf16
//   [6144, 8192)     transpose W_out [2048][1024] -> WoutT [1024][2048] bf16
//   [8192, 9216)     W_xproj [2048][33] -> WxpT [128][2048] bf16, zero-pad
// ---------------------------------------------------------------------------
__device__ __forceinline__ void transpose_tile(const float* __restrict__ in,
                                               u16* __restrict__ out,
                                               int R, int C, int n0, int k0,
                                               int tid) {
    __shared__ float tile[32][33];
    const int tx = tid & 31, ty = tid >> 5;   // 32x8
    #pragma unroll
    for (int i = 0; i < 32; i += 8)
        tile[ty + i][tx] = in[(size_t)(k0 + ty + i) * C + n0 + tx];
    __syncthreads();
    #pragma unroll
    for (int i = 0; i < 32; i += 8)
        out[(size_t)(n0 + ty + i) * R + k0 + tx] = f2bf(tile[tx][ty + i]);
}

__global__ __launch_bounds__(256)
void prep_all(const float* __restrict__ x, const float* __restrict__ W_in,
              const float* __restrict__ W_out, const float* __restrict__ W_xproj,
              u16* __restrict__ xbf, u16* __restrict__ WinT,
              u16* __restrict__ WoutT, u16* __restrict__ WxpT) {
    const int tid = threadIdx.x;
    int blk = blockIdx.x;
    if (blk < 2048) {                          // cast x (2M elems, 4/thread)
        int base = (blk * 256 + tid) * 4;
        float4 v = *(const float4*)(x + base);
        ushort4 o;
        o.x = f2bf(v.x); o.y = f2bf(v.y); o.z = f2bf(v.z); o.w = f2bf(v.w);
        *(ushort4*)(xbf + base) = o;
        return;
    }
    blk -= 2048;
    if (blk < 4096) {                          // W_in: R=1024, C=4096
        transpose_tile(W_in, WinT, 1024, 4096, (blk & 127) * 32, (blk >> 7) * 32, tid);
        return;
    }
    blk -= 4096;
    if (blk < 2048) {                          // W_out: R=2048, C=1024
        transpose_tile(W_out, WoutT, 2048, 1024, (blk & 31) * 32, (blk >> 5) * 32, tid);
        return;
    }
    blk -= 2048;
    {                                          // WxpT pad+transpose
        int gid = blk * 256 + tid;
        int k = gid & 2047;
        int n = gid >> 11;
        WxpT[(size_t)n * 2048 + k] = (n < 33) ? f2bf(W_xproj[(size_t)k * 33 + n]) : (u16)0;
    }
}

// ---------------------------------------------------------------------------
// MFMA GEMM (R10-verified): C[M][N] = A[M][K] * Bt[N][K]^T, 128x128 tile,
// BK=64 staged as two 128x32 half-buffers (m97-proven 64B LDS row stride;
// global_load_lds forbids padding). OUT_MODE: 0 = f32 partial at
// blockIdx.z*M*N (split-K, atomic-free), 2 = bf16 store (gridDim.z==1).
// ---------------------------------------------------------------------------
template <int OUT_MODE>
__global__ __launch_bounds__(256)
void gemm_bt(const u16* __restrict__ A, const u16* __restrict__ Bt,
             void* __restrict__ Cv, int M, int N, int K) {
    __shared__ __align__(16) u16 As[2][128 * 32];
    __shared__ __align__(16) u16 Bs[2][128 * 32];

    const int tid  = threadIdx.x;
    const int lane = tid & 63;
    const int w    = tid >> 6;
    const int wm   = (w >> 1) * 64;
    const int wn   = (w & 1) * 64;
    const int r    = lane & 15;
    const int q    = lane >> 4;
    const int m0   = blockIdx.x * 128;
    const int n0   = blockIdx.y * 128;
    const int kChunk = K / gridDim.z;
    const int k0   = blockIdx.z * kChunk;

    f32x4 acc[4][4];
    #pragma unroll
    for (int i = 0; i < 4; ++i)
        #pragma unroll
        for (int j = 0; j < 4; ++j)
            acc[i][j] = (f32x4){0.f, 0.f, 0.f, 0.f};

    for (int kk = k0; kk < k0 + kChunk; kk += 64) {
        __syncthreads();
        #pragma unroll
        for (int i = 0; i < 4; ++i) {
            int half = i >> 1;
            int c    = ((i & 1) << 8) + tid;
            int row  = c >> 2;
            int kc   = (c & 3) << 3;
            int wb   = (((i & 1) << 8) + (tid & 192)) * 8;
            gload_lds16(&A[(size_t)(m0 + row) * K + kk + half * 32 + kc],
                        &As[half][wb]);
            gload_lds16(&Bt[(size_t)(n0 + row) * K + kk + half * 32 + kc],
                        &Bs[half][wb]);
        }
        __syncthreads();

        #pragma unroll
        for (int half = 0; half < 2; ++half) {
            short8 af[4], bf[4];
            #pragma unroll
            for (int mt = 0; mt < 4; ++mt)
                af[mt] = *(const short8*)(&As[half][(wm + mt * 16 + r) * 32 + q * 8]);
            #pragma unroll
            for (int nt = 0; nt < 4; ++nt)
                bf[nt] = *(const short8*)(&Bs[half][(wn + nt * 16 + r) * 32 + q * 8]);

            #pragma unroll
            for (int mt = 0; mt < 4; ++mt)
                #pragma unroll
                for (int nt = 0; nt < 4; ++nt)
                    acc[mt][nt] = __builtin_amdgcn_mfma_f32_16x16x32_bf16(
                        af[mt], bf[nt], acc[mt][nt], 0, 0, 0);
        }
    }

    float* Cp = (float*)Cv + (size_t)blockIdx.z * M * N;
    #pragma unroll
    for (int mt = 0; mt < 4; ++mt) {
        #pragma unroll
        for (int nt = 0; nt < 4; ++nt) {
            #pragma unroll
            for (int i = 0; i < 4; ++i) {
                int row = m0 + wm + mt * 16 + q * 4 + i;
                int col = n0 + wn + nt * 16 + r;
                float v = acc[mt][nt][i];
                size_t idx = (size_t)row * N + col;
                if (OUT_MODE == 0) Cp[idx] = v;
                else               ((u16*)Cv)[idx] = f2bf(v);
            }
        }
    }
}

// reduce split-K partials: o4[i] = sum_z p4[z*n4+i]   (float4 lanes)
// Separate kernel ON PURPOSE — kernel boundary is the cheap device-scope
// fence on CDNA4 (R12: intra-kernel __threadfence cost ~100us across XCDs).
__global__ __launch_bounds__(256)
void reduce_parts(const float4* __restrict__ p, float4* __restrict__ o,
                  int n4, int parts) {
    int i = blockIdx.x * 256 + threadIdx.x;
    if (i >= n4) return;
    float4 s = p[i];
    for (int z = 1; z < parts; ++z) {
        float4 v = p[(size_t)z * n4 + i];
        s.x += v.x; s.y += v.y; s.z += v.z; s.w += v.w;
    }
    o[i] = s;
}

// ---------------------------------------------------------------------------
// Depthwise causal conv (4-tap) + bias + SiLU.
// ---------------------------------------------------------------------------
__global__ __launch_bounds__(256)
void conv_silu(const u16* __restrict__ xz, const float* __restrict__ cw,
               const float* __restrict__ cb, u16* __restrict__ xcb) {
    const int d   = blockIdx.x * 256 + threadIdx.x;
    const int tok = blockIdx.y;
    const int b   = tok >> 10;
    const int t   = tok & 1023;
    float s = cb[d];
    #pragma unroll
    for (int k = 0; k < 4; ++k) {
        int tt = t - 3 + k;
        if (tt >= 0)
            s += bf2f(xz[(size_t)(b * 1024 + tt) * 4096 + d]) * cw[d * 4 + k];
    }
    float sl = s / (1.f + __expf(-s));
    xcb[(size_t)tok * 2048 + d] = f2bf(sl);
}

// dA powers tree: dA[n] = e1^(n+1), dep depth ~3.
__device__ __forceinline__ void pow_tree(float e1, float* dA) {
    float e2 = e1 * e1, e4 = e2 * e2, e8 = e4 * e4;
    dA[0] = e1;       dA[1] = e2;       dA[2] = e2 * e1;  dA[3] = e4;
    dA[4] = e4 * e1;  dA[5] = e4 * e2;  dA[6] = e4 * dA[2]; dA[7] = e8;
    dA[8] = e8 * e1;  dA[9] = e8 * e2;  dA[10] = e8 * dA[2]; dA[11] = e8 * e4;
    dA[12] = e8 * dA[4]; dA[13] = e8 * dA[5]; dA[14] = e8 * dA[6]; dA[15] = e8 * e8;
}

// ---------------------------------------------------------------------------
// Chunked selective scan (R10-verified). Lanes over d; 16 states in regs;
// xp tile in LDS. xp row stride 128: [0]=dt_raw, [1..16]=B, [17..32]=C.
// Per-chunk summary: hend[16] + Sdl (Sum delta); prod exp(a*dl) == exp(a*Sum).
// ---------------------------------------------------------------------------
__global__ __launch_bounds__(256)
void scan_pass1(const u16* __restrict__ xcb, const float* __restrict__ xp,
                const float* __restrict__ W_dt, const float* __restrict__ b_dt,
                const float* __restrict__ A_log,
                float* __restrict__ Sdl, float* __restrict__ hend) {
    const int c  = blockIdx.x;
    const int dg = blockIdx.y;
    const int b  = blockIdx.z;
    const int tid = threadIdx.x;
    const int d  = dg * 256 + tid;
    const int tok0 = b * 1024 + c * TC;

    __shared__ float xps[TC][36];
    for (int e = tid; e < TC * 33; e += 256) {
        int t = (e * 993) >> 15;     // e/33 for e<528
        int j = e - t * 33;
        xps[t][j] = xp[(size_t)(tok0 + t) * 128 + j];
    }
    __syncthreads();

    float a[16];
    bool fast = true;
    #pragma unroll
    for (int n = 0; n < 16; ++n) {
        a[n] = -__expf(A_log[n]);
        fast = fast && (__builtin_fabsf(a[n] + (float)(n + 1)) < 1e-3f * (n + 1));
    }

    const float wdt = W_dt[d];
    const float bdt = b_dt[d];

    float h[16];
    #pragma unroll
    for (int n = 0; n < 16; ++n) h[n] = 0.f;
    float sdl = 0.f;

    for (int t = 0; t < TC; ++t) {
        const int tok = tok0 + t;
        const float dl = softplus_f(xps[t][0] * wdt + bdt);
        sdl += dl;
        const float xv = bf2f(xcb[(size_t)tok * 2048 + d]);
        const float wv = dl * xv;
        if (fast) {
            float dA[16];
            pow_tree(__expf(-dl), dA);
            #pragma unroll
            for (int n = 0; n < 16; ++n)
                h[n] = fmaf(dA[n], h[n], wv * xps[t][1 + n]);
        } else {
            #pragma unroll
            for (int n = 0; n < 16; ++n)
                h[n] = fmaf(__expf(dl * a[n]), h[n], wv * xps[t][1 + n]);
        }
    }

    Sdl[(size_t)(b * NC + c) * 2048 + d] = sdl;
    #pragma unroll
    for (int n = 0; n < 16; ++n)
        hend[((size_t)((b * NC + c) * 16 + n)) * 2048 + d] = h[n];
}

// Sequential combine (coalesced over d); writes separate __restrict__ hstart
// (R10: alias-free lets loads pipeline past stores).
__global__ __launch_bounds__(256)
void scan_combine(const float* __restrict__ Sdl, const float* __restrict__ A_log,
                  const float* __restrict__ hend, float* __restrict__ hstart) {
    const int gid = blockIdx.x * 256 + threadIdx.x;   // 2*16*2048 threads
    const int d = gid & 2047;
    const int n = (gid >> 11) & 15;
    const int b = gid >> 15;
    const float an = -__expf(A_log[n]);
    float H = 0.f;
    #pragma unroll 4
    for (int c = 0; c < NC; ++c) {
        size_t cidx = (size_t)(b * NC + c);
        float s  = Sdl[cidx * 2048 + d];
        size_t idx = (cidx * 16 + n) * 2048 + d;
        float he = hend[idx];
        hstart[idx] = H;               // start state for chunk c
        H = fmaf(__expf(an * s), H, he);
    }
}

__global__ __launch_bounds__(256)
void scan_pass2(const u16* __restrict__ xcb, const float* __restrict__ xp,
                const float* __restrict__ W_dt, const float* __restrict__ b_dt,
                const float* __restrict__ A_log, const float* __restrict__ Hstart,
                const float* __restrict__ Dp, const u16* __restrict__ xz,
                u16* __restrict__ ybuf) {
    const int c  = blockIdx.x;
    const int dg = blockIdx.y;
    const int b  = blockIdx.z;
    const int tid = threadIdx.x;
    const int d  = dg * 256 + tid;
    const int tok0 = b * 1024 + c * TC;

    __shared__ float xps[TC][36];
    for (int e = tid; e < TC * 33; e += 256) {
        int t = (e * 993) >> 15;
        int j = e - t * 33;
        xps[t][j] = xp[(size_t)(tok0 + t) * 128 + j];
    }
    __syncthreads();

    float a[16];
    bool fast = true;
    #pragma unroll
    for (int n = 0; n < 16; ++n) {
        a[n] = -__expf(A_log[n]);
        fast = fast && (__builtin_fabsf(a[n] + (float)(n + 1)) < 1e-3f * (n + 1));
    }

    const float wdt = W_dt[d];
    const float bdt = b_dt[d];

    float h[16];
    #pragma unroll
    for (int n = 0; n < 16; ++n)
        h[n] = Hstart[((size_t)((b * NC + c) * 16 + n)) * 2048 + d];

    const float Dd = Dp[d];
    for (int t = 0; t < TC; ++t) {
        const int tok = tok0 + t;
        const float dl = softplus_f(xps[t][0] * wdt + bdt);
        const float xv = bf2f(xcb[(size_t)tok * 2048 + d]);
        const float wv = dl * xv;
        if (fast) {
            float dA[16];
            pow_tree(__expf(-dl), dA);
            #pragma unroll
            for (int n = 0; n < 16; ++n)
                h[n] = fmaf(dA[n], h[n], wv * xps[t][1 + n]);
        } else {
            #pragma unroll
            for (int n = 0; n < 16; ++n)
                h[n] = fmaf(__expf(dl * a[n]), h[n], wv * xps[t][1 + n]);
        }
        float y0 = 0.f, y1 = 0.f, y2 = 0.f, y3 = 0.f;
        #pragma unroll
        for (int n = 0; n < 16; n += 4) {
            y0 = fmaf(h[n + 0], xps[t][17 + n + 0], y0);
            y1 = fmaf(h[n + 1], xps[t][17 + n + 1], y1);
            y2 = fmaf(h[n + 2], xps[t][17 + n + 2], y2);
            y3 = fmaf(h[n + 3], xps[t][17 + n + 3], y3);
        }
        float y = (y0 + y1) + (y2 + y3);
        y = fmaf(Dd, xv, y);
        float zv = bf2f(xz[(size_t)tok * 4096 + 2048 + d]);
        float sz = zv / (1.f + __expf(-zv));
        ybuf[(size_t)tok * 2048 + d] = f2bf(y * sz);
    }
}

// ---------------------------------------------------------------------------
extern "C" void kernel_launch(void* const* d_in, const int* in_sizes, int n_in,
                              void* d_out, int out_size, void* d_ws, size_t ws_size,
                              hipStream_t stream) {
    const float* x       = (const float*)d_in[0];
    const float* W_in    = (const float*)d_in[1];
    const float* conv_w  = (const float*)d_in[2];
    const float* conv_b  = (const float*)d_in[3];
    const float* W_xproj = (const float*)d_in[4];
    const float* W_dt    = (const float*)d_in[5];
    const float* b_dt    = (const float*)d_in[6];
    const float* A_log   = (const float*)d_in[7];
    const float* Dp      = (const float*)d_in[8];
    const float* W_out   = (const float*)d_in[9];
    float* out = (float*)d_out;                     // [2][1024][1024] f32

    char* ws = (char*)d_ws;
    size_t off = 0;
    auto alloc = [&](size_t bytes) -> void* {
        void* p = ws + off;
        off += (bytes + 255) & ~(size_t)255;
        return p;
    };

    u16*   xbf    = (u16*)  alloc((size_t)NTOK * 1024 * 2);
    u16*   xz     = (u16*)  alloc((size_t)NTOK * 4096 * 2);
    u16*   WinT   = (u16*)  alloc((size_t)4096 * 1024 * 2);
    u16*   WoutT  = (u16*)  alloc((size_t)1024 * 2048 * 2);
    u16*   WxpT   = (u16*)  alloc((size_t)128 * 2048 * 2);
    u16*   xcb    = (u16*)  alloc((size_t)NTOK * 2048 * 2);
    float* xpp    = (float*)alloc((size_t)8 * NTOK * 128 * 4);     //  8.4 MB
    float* xp     = (float*)alloc((size_t)NTOK * 128 * 4);
    u16*   ybuf   = (u16*)  alloc((size_t)NTOK * 2048 * 2);
    float* Sdl    = (float*)alloc((size_t)2 * NC * 2048 * 4);
    float* hend   = (float*)alloc((size_t)2 * NC * 16 * 2048 * 4); // 16.8 MB
    float* hstart = (float*)alloc((size_t)2 * NC * 16 * 2048 * 4); // 16.8 MB
    float* op     = (float*)alloc((size_t)4 * NTOK * 1024 * 4);    // 33.6 MB

    const int ws_ok = (off <= ws_size);   // ws = 256 MiB; total ~120 MB
    if (ws_ok) {
        // fused prep: cast x (float4), transpose W_in/W_out, pad W_xproj
        prep_all<<<9216, 256, 0, stream>>>(x, W_in, W_out, W_xproj,
                                           xbf, WinT, WoutT, WxpT);

        // GEMM1: xz = xbf @ W_in (bf16 out), 512 blocks, 16 K-rounds
        gemm_bt<2><<<dim3(16, 32, 1), 256, 0, stream>>>(xbf, WinT, xz,
                                                        2048, 4096, 1024);

        conv_silu<<<dim3(8, NTOK), 256, 0, stream>>>(xz, conv_w, conv_b, xcb);

        // xproj: split-K=8 partials (atomic-free), then reduce
        gemm_bt<0><<<dim3(16, 1, 8), 256, 0, stream>>>(xcb, WxpT, xpp,
                                                       2048, 128, 2048);
        reduce_parts<<<(NTOK * 128 / 4) / 256, 256, 0, stream>>>(
            (const float4*)xpp, (float4*)xp, NTOK * 128 / 4, 8);

        // chunked scan (NC=64: 1024 blocks/pass, 4 blocks/CU)
        scan_pass1<<<dim3(NC, 8, 2), 256, 0, stream>>>(xcb, xp, W_dt, b_dt, A_log,
                                                       Sdl, hend);
        scan_combine<<<(2 * 16 * 2048) / 256, 256, 0, stream>>>(Sdl, A_log,
                                                                hend, hstart);
        scan_pass2<<<dim3(NC, 8, 2), 256, 0, stream>>>(xcb, xp, W_dt, b_dt, A_log,
                                                       hstart, Dp, xz, ybuf);

        // GEMM2: split-K=4 partials (atomic-free), then reduce into d_out
        gemm_bt<0><<<dim3(16, 8, 4), 256, 0, stream>>>(ybuf, WoutT, op,
                                                       2048, 1024, 2048);
        reduce_parts<<<(NTOK * 1024 / 4) / 256, 256, 0, stream>>>(
            (const float4*)op, (float4*)out, NTOK * 1024 / 4, 4);
    }
}